// Round 9
// baseline (257.614 us; speedup 1.0000x reference)
//
#include <hip/hip_runtime.h>

// Attention_86423331930517 — MI355X bf16-MFMA implementation, round 9.
// B=16, H=W=64, C=512, HW=4096, P=1024 pooled pixels, D=64 (qk dim), DV=256 (v dim).
// Round-9 change: gemm_out only. Round-8 post-mortem: VGPR_Count=64 showed the
// compiler register-minimized the kernel, sinking each x-load next to its store
// (full HBM latency exposed ~128x per wave). Now: __launch_bounds__(256,2) to lift
// the register budget, explicit xvA/xvB double-buffered x-prefetch (issue it+1's
// loads before it's MFMA chain), bw loads inlined pairwise. Everything else = R8.

#define DEVI static __device__ __forceinline__

typedef float f32x4  __attribute__((ext_vector_type(4)));
typedef float f32x16 __attribute__((ext_vector_type(16)));
typedef short bf16x8 __attribute__((ext_vector_type(8)));

DEVI short f2bf(float f) {
  union { float f; unsigned u; } v; v.f = f;
  unsigned r = v.u + 0x7FFFu + ((v.u >> 16) & 1u);   // RNE
  return (short)(r >> 16);
}
DEVI float b2f(short s) {
  union { unsigned u; float f; } v; v.u = ((unsigned)(unsigned short)s) << 16; return v.f;
}
DEVI unsigned cvtpk(float lo, float hi) {        // dst = {bf16(lo) | bf16(hi)<<16}, RNE
  unsigned r;
  asm("v_cvt_pk_bf16_f32 %0, %1, %2" : "=v"(r) : "v"(lo), "v"(hi));
  return r;
}
DEVI f32x4 mfma16(bf16x8 a, bf16x8 b, f32x4 c) {
  return __builtin_amdgcn_mfma_f32_16x16x32_bf16(a, b, c, 0, 0, 0);
}
DEVI f32x16 mfma32(bf16x8 a, bf16x8 b, f32x16 c) {
  return __builtin_amdgcn_mfma_f32_32x32x16_bf16(a, b, c, 0, 0, 0);
}
DEVI void gload16(const short* gsrc, short* lds) {
  __builtin_amdgcn_global_load_lds(
      (const __attribute__((address_space(1))) void*)gsrc,
      (__attribute__((address_space(3))) void*)lds, 16, 0, 0);
}

// ---------------- weights: cast to bf16 and transpose so B-operand rows are k-contiguous
__global__ __launch_bounds__(256) void prep_weights(
    const float* __restrict__ Wf, const float* __restrict__ Wg,
    const float* __restrict__ Wh, const float* __restrict__ Wo,
    short* __restrict__ WfT, short* __restrict__ WgT,
    short* __restrict__ WhT, short* __restrict__ WoT) {
  int i = blockIdx.x * 256 + threadIdx.x;   // 0..393215 exactly
  const float* src; short* dst; int K, N, e;
  if (i < 32768)       { src = Wf; dst = WfT; K = 512; N = 64;  e = i; }
  else if (i < 65536)  { src = Wg; dst = WgT; K = 512; N = 64;  e = i - 32768; }
  else if (i < 196608) { src = Wh; dst = WhT; K = 512; N = 256; e = i - 65536; }
  else                 { src = Wo; dst = WoT; K = 256; N = 512; e = i - 196608; }
  int n = e / K, k = e - n * K;            // dst[n][k] = src[k][n]
  dst[e] = f2bf(src[(long)k * N + n]);
}

// ---------------- staging helper: tile of `rows` x 64 bf16 into XOR-swizzled LDS -------
template<bool SRC_F32>
DEVI void stage64(short* lds, const void* gsrc, int rows, int stride, int tid) {
  const int chunks = rows * 8;
  for (int c = tid; c < chunks; c += 256) {
    int row = c >> 3, slot = c & 7;
    int dstb = row*128 + ((slot ^ (row & 7)) << 4);
    if (SRC_F32) {
      const float* s = (const float*)gsrc + (long)row*stride + slot*8;
      float4 u0 = *(const float4*)s;
      float4 u1 = *(const float4*)(s + 4);
      union { unsigned u[4]; bf16x8 v; } pk;
      pk.u[0] = cvtpk(u0.x, u0.y); pk.u[1] = cvtpk(u0.z, u0.w);
      pk.u[2] = cvtpk(u1.x, u1.y); pk.u[3] = cvtpk(u1.z, u1.w);
      *(bf16x8*)((char*)lds + dstb) = pk.v;
    } else {
      *(bf16x8*)((char*)lds + dstb) =
          *(const bf16x8*)((const short*)gsrc + (long)row*stride + slot*8);
    }
  }
}

// ---------------- generic K=512 GEMM: C[M,Nfull] = A[M,512] @ BT[N,512]^T (bf16 out) ---
// cscale: applied at C-write (f-GEMM uses log2(e) so attn can use raw exp2).
template<bool A_F32, bool POOL>
__global__ __launch_bounds__(256) void gemm_k512(const void* __restrict__ A,
    const short* __restrict__ BT, short* __restrict__ C, int Nfull,
    short* __restrict__ xp, float cscale) {
  __shared__ short As[128*64];
  __shared__ short Bs[64*64];
  const int m0 = blockIdx.x * 128;
  const int n0 = blockIdx.y * 64;
  const int tid = threadIdx.x, w = tid >> 6, lane = tid & 63;
  const int l15 = lane & 15, lhi = lane >> 4;
  const int wr = w >> 1, wc = w & 1;
  f32x4 acc[4][2] = {};
  for (int kt = 0; kt < 8; ++kt) {
    const int k0 = kt * 64;
    if constexpr (A_F32)
      stage64<true >(As, (const float*)A + (long)m0*512 + k0, 128, 512, tid);
    else
      stage64<false>(As, (const short*)A + (long)m0*512 + k0, 128, 512, tid);
    stage64<false>(Bs, BT + (long)n0*512 + k0, 64, 512, tid);
    __syncthreads();
    if constexpr (POOL) {
      const long pr0 = (long)(m0 >> 12)*1024 + ((m0 & 4095) >> 7)*32;
      int wp = tid >> 3, cs = tid & 7;
      const char* Ab = (const char*)As;
      bf16x8 v00 = *(const bf16x8*)(Ab + (2*wp  )*128 + ((cs ^ ((2*wp  )&7))<<4));
      bf16x8 v01 = *(const bf16x8*)(Ab + (2*wp+1)*128 + ((cs ^ ((2*wp+1)&7))<<4));
      bf16x8 v10 = *(const bf16x8*)(Ab + (64+2*wp)*128 + ((cs ^ ((2*wp  )&7))<<4));
      bf16x8 v11 = *(const bf16x8*)(Ab + (65+2*wp)*128 + ((cs ^ ((2*wp+1)&7))<<4));
      float s[8];
      #pragma unroll
      for (int j = 0; j < 8; ++j)
        s[j] = 0.25f*(b2f(v00[j])+b2f(v01[j])+b2f(v10[j])+b2f(v11[j]));
      union { unsigned u[4]; bf16x8 v; } pk;
      pk.u[0] = cvtpk(s[0], s[1]); pk.u[1] = cvtpk(s[2], s[3]);
      pk.u[2] = cvtpk(s[4], s[5]); pk.u[3] = cvtpk(s[6], s[7]);
      *(bf16x8*)(xp + (pr0 + wp)*512 + k0 + cs*8) = pk.v;
    }
    bf16x8 af[4][2], bfr[2][2];
    #pragma unroll
    for (int mi = 0; mi < 4; ++mi)
      #pragma unroll
      for (int ks = 0; ks < 2; ++ks) {
        int m = wr*64 + mi*16 + l15;
        int slot = lhi + ks*4;
        af[mi][ks] = *(const bf16x8*)((const char*)As + m*128 + ((slot ^ (m & 7)) << 4));
      }
    #pragma unroll
    for (int ni = 0; ni < 2; ++ni)
      #pragma unroll
      for (int ks = 0; ks < 2; ++ks) {
        int n = wc*32 + ni*16 + l15;
        int slot = lhi + ks*4;
        bfr[ni][ks] = *(const bf16x8*)((const char*)Bs + n*128 + ((slot ^ (n & 7)) << 4));
      }
    #pragma unroll
    for (int ks = 0; ks < 2; ++ks)
      #pragma unroll
      for (int mi = 0; mi < 4; ++mi)
        #pragma unroll
        for (int ni = 0; ni < 2; ++ni)
          acc[mi][ni] = mfma16(af[mi][ks], bfr[ni][ks], acc[mi][ni]);
    __syncthreads();
  }
  #pragma unroll
  for (int mi = 0; mi < 4; ++mi)
    #pragma unroll
    for (int ni = 0; ni < 2; ++ni)
      #pragma unroll
      for (int r = 0; r < 4; ++r) {
        long row = m0 + wr*64 + mi*16 + lhi*4 + r;
        int col = n0 + wc*32 + ni*16 + l15;
        C[row * (long)Nfull + col] = f2bf(acc[mi][ni][r] * cscale);
      }
}

// ---------------- h[16*1024,256] -> hT[16*256,1024] (bf16 transpose) -------------------
__global__ __launch_bounds__(256) void transpose_h(const short* __restrict__ h,
                                                   short* __restrict__ hT) {
  __shared__ short t[64][72];
  const int k0 = blockIdx.x * 64, n0 = blockIdx.y * 64, b = blockIdx.z;
  const int tid = threadIdx.x;
  {
    int row = tid >> 2, cch = (tid & 3) * 16;
    const short* src = h + ((long)b*1024 + k0 + row) * 256 + n0 + cch;
    *(bf16x8*)&t[row][cch]     = *(const bf16x8*)src;
    *(bf16x8*)&t[row][cch + 8] = *(const bf16x8*)(src + 8);
  }
  __syncthreads();
  {
    int n = tid >> 2, kch = (tid & 3) * 16;
    bf16x8 lo, hi;
    #pragma unroll
    for (int j = 0; j < 8; ++j) { lo[j] = t[kch + j][n]; hi[j] = t[kch + 8 + j][n]; }
    short* dst = hT + ((long)b*256 + n0 + n) * 1024 + k0 + kch;
    *(bf16x8*)dst       = lo;
    *(bf16x8*)(dst + 8) = hi;
  }
}

// ---------------- fused attention, 32x32x16 MFMA, QBLK=128, 4 waves, 2 blocks/CU -------
// Swapped QK^T: S = mfma(g, f) -> q=lane&31 lane-local (f pre-scaled by log2e -> raw
// exp2). P assembled IN-REGISTER via v_cvt_pk_bf16_f32 + v_permlane32_swap_b32.
// Swapped PV: y = mfma(hT, P). Counted s_waitcnt vmcnt(10) + raw barriers.
// Flat grid 512 with XCD swizzle: xcd=bid&7 owns batches {2*xcd, 2*xcd+1} -> K/V L2-local.
// Epilogue: normalize, per-wave LDS round-trip -> coalesced y stores.
__global__ __launch_bounds__(256, 2) void attn_kernel(const short* __restrict__ f,
    const short* __restrict__ g, const short* __restrict__ hT,
    short* __restrict__ y) {
  extern __shared__ __align__(16) char smem[];
  const int bid = blockIdx.x;
  const int xcd = bid & 7, idx = bid >> 3;
  const int b = xcd*2 + (idx >> 5);
  const int q0 = (idx & 31) * 128;
  const int tid = threadIdx.x, w = tid >> 6, lane = tid & 63;
  const int l31 = lane & 31, hi = lane >> 5;

  bf16x8 fq[4];
  {
    const short* frow = f + ((long)b*4096 + q0 + w*32 + l31) * 64;
    #pragma unroll
    for (int ks = 0; ks < 4; ++ks) fq[ks] = *(const bf16x8*)(frow + ks*16 + hi*8);
  }

  f32x16 acc2[8] = {};     // [nc2] : n = nc2*32 + (g&3)+8*(g>>2)+4*hi, q = l31
  float rsq = 0.f;

  auto stage = [&](int buf, int kt) {   // 10 gload16 per wave per call
    const int k0 = kt * 64;
    short* gbuf = (short*)(smem + buf*8192);
    short* hbuf = (short*)(smem + 16384 + buf*32768);
    #pragma unroll
    for (int it = 0; it < 2; ++it) {          // g: 64 rows x 8 slots = 512 chunks
      int c = it*256 + w*64 + lane;
      int row = c >> 3, gslot = (c & 7) ^ (row & 7);
      gload16(g + ((long)b*1024 + k0 + row)*64 + gslot*8, gbuf + (it*256 + w*64)*8);
    }
    #pragma unroll
    for (int it = 0; it < 8; ++it) {          // hT: 256 rows x 8 slots = 2048 chunks
      int c = it*256 + w*64 + lane;
      int row = c >> 3, gslot = (c & 7) ^ (row & 7);
      gload16(hT + ((long)b*256 + row)*1024 + k0 + gslot*8, hbuf + (it*256 + w*64)*8);
    }
  };

  stage(0, 0);
  int cur = 0;
  for (int kt = 0; kt < 16; ++kt) {
    if (kt < 15) {
      stage(cur ^ 1, kt + 1);
      // wait only for CURRENT tile's 10 loads (issued last iter); next's 10 stay in flight
      asm volatile("s_waitcnt vmcnt(10)" ::: "memory");
    } else {
      asm volatile("s_waitcnt vmcnt(0)" ::: "memory");
    }
    __builtin_amdgcn_s_barrier();          // current buffer visible to all waves
    const char* gcur = (const char*)(smem + cur*8192);
    const char* hcur = (const char*)(smem + 16384 + cur*32768);
    // ---- QK^T (swapped) + exp2 + in-register P^T fragment assembly ----
    bf16x8 pa[4];
    #pragma unroll
    for (int kc2 = 0; kc2 < 2; ++kc2) {
      f32x16 s2 = {};
      #pragma unroll
      for (int ks = 0; ks < 4; ++ks) {
        int key = kc2*32 + l31;
        bf16x8 gb = *(const bf16x8*)(gcur + key*128 + (((ks*2 + hi) ^ (l31 & 7)) << 4));
        s2 = mfma32(gb, fq[ks], s2);
      }
      #pragma unroll
      for (int fh = 0; fh < 2; ++fh) {
        const int G = fh*8;
        float e0 = exp2f(s2[G+0]), e1 = exp2f(s2[G+1]);
        float e2 = exp2f(s2[G+2]), e3 = exp2f(s2[G+3]);
        float e4 = exp2f(s2[G+4]), e5 = exp2f(s2[G+5]);
        float e6 = exp2f(s2[G+6]), e7 = exp2f(s2[G+7]);
        rsq += ((e0 + e1) + (e2 + e3)) + ((e4 + e5) + (e6 + e7));
        unsigned a0 = cvtpk(e0, e1), a1 = cvtpk(e2, e3);
        unsigned b0 = cvtpk(e4, e5), b1 = cvtpk(e6, e7);
        asm volatile("v_permlane32_swap_b32 %0, %1" : "+v"(b0), "+v"(a0));
        asm volatile("v_permlane32_swap_b32 %0, %1" : "+v"(b1), "+v"(a1));
        union { unsigned u[4]; bf16x8 v; } pk;
        pk.u[0] = a0; pk.u[1] = a1; pk.u[2] = b0; pk.u[3] = b1;
        pa[kc2*2 + fh] = pk.v;
      }
    }
    // ---- PV (swapped), P from registers ----
    __builtin_amdgcn_s_setprio(1);
    #pragma unroll
    for (int ks = 0; ks < 4; ++ks) {
      #pragma unroll
      for (int nc2 = 0; nc2 < 8; ++nc2) {
        int n = nc2*32 + l31;
        bf16x8 hb = *(const bf16x8*)(hcur + n*128 + (((ks*2 + hi) ^ (l31 & 7)) << 4));
        acc2[nc2] = mfma32(hb, pa[ks], acc2[nc2]);
      }
    }
    __builtin_amdgcn_s_setprio(0);
    __builtin_amdgcn_s_barrier();          // all waves done reading cur before overwrite
    cur ^= 1;
  }
  // ---- normalize + per-wave LDS round-trip -> coalesced y stores ----
  rsq += __shfl_xor(rsq, 32);
  float ri = 1.f / rsq;
  short* yw = (short*)(smem + w*16384);
  #pragma unroll
  for (int nc2 = 0; nc2 < 8; ++nc2) {
    #pragma unroll
    for (int fh = 0; fh < 2; ++fh) {
      const int G = fh*8;
      unsigned a0 = cvtpk(acc2[nc2][G+0]*ri, acc2[nc2][G+1]*ri);
      unsigned a1 = cvtpk(acc2[nc2][G+2]*ri, acc2[nc2][G+3]*ri);
      unsigned b0 = cvtpk(acc2[nc2][G+4]*ri, acc2[nc2][G+5]*ri);
      unsigned b1 = cvtpk(acc2[nc2][G+6]*ri, acc2[nc2][G+7]*ri);
      asm volatile("v_permlane32_swap_b32 %0, %1" : "+v"(b0), "+v"(a0));
      asm volatile("v_permlane32_swap_b32 %0, %1" : "+v"(b1), "+v"(a1));
      union { unsigned u[4]; bf16x8 v; } pk;
      pk.u[0] = a0; pk.u[1] = a1; pk.u[2] = b0; pk.u[3] = b1;
      int s = (nc2*2 + fh)*2 + hi;                       // logical 16B slot 0..31
      *(bf16x8*)(yw + l31*256 + ((s ^ l31) * 8)) = pk.v; // row=l31 (q), swizzled slot
    }
  }
  const long qb = (long)b*4096 + q0 + w*32;
  #pragma unroll
  for (int i = 0; i < 16; ++i) {
    int row = i*2 + hi;
    int s = l31 ^ row;                                   // logical slot at LDS pos l31
    bf16x8 v = *(const bf16x8*)(yw + row*256 + l31*8);
    *(bf16x8*)(y + (qb + row)*256 + s*8) = v;
  }
}

// ---------------- out = y[65536,256] @ WoT[512,256]^T + x (f32 out), streaming ---------
// UN-swapped orientation: A = y rows (LDS, staged once), B = WoT cols (L2-resident),
// C/D col = lane&31 -> x-loads and out-stores are contiguous 128B segments.
// Round-9: __launch_bounds__(256,2) lifts the register budget (R8's VGPR=64 allocation
// sank x-loads next to stores -> serial latency); explicit xvA/xvB double-buffered
// x-prefetch issues iteration it+1's loads before it's MFMA chain (T14).
__global__ __launch_bounds__(256, 2) void gemm_out(const short* __restrict__ y,
    const short* __restrict__ WoT, const float* __restrict__ x,
    float* __restrict__ out) {
  __shared__ short ys[64*256];   // 32 KB, row-major with 16B-slot XOR swizzle
  const int q0 = blockIdx.x * 64;
  const int tid = threadIdx.x, w = tid >> 6, lane = tid & 63;
  const int l31 = lane & 31, hi = lane >> 5;
  #pragma unroll
  for (int it = 0; it < 8; ++it) {
    int c = it*256 + tid;
    int row = c >> 5, gslot = (c & 31) ^ (row & 31);
    gload16(y + ((long)q0 + row)*256 + gslot*8, ys + c*8);
  }
  asm volatile("s_waitcnt vmcnt(0)" ::: "memory");
  __builtin_amdgcn_s_barrier();
  const int wr = w >> 1, wc = w & 1;
  // A-frags: wave owns rows wr*32..+31; lane row = qr, k = kk*16 + hi*8 + j
  const int qr = wr*32 + l31;
  bf16x8 ya[16];
  #pragma unroll
  for (int kk = 0; kk < 16; ++kk)
    ya[kk] = *(const bf16x8*)(ys + qr*256 + (((kk*2 + hi) ^ l31) * 8));
  // per-lane base: row-block wr*32, col-range wc*256, lane col offset l31
  const long obase = (long)q0 * 512;
  const float* xw = x   + obase + (long)wr*32*512 + wc*256 + l31;
  float*       ow = out + obase + (long)wr*32*512 + wc*256 + l31;
  float xvA[16], xvB[16];
  #pragma unroll
  for (int r = 0; r < 16; ++r) {
    int rowoff = (r&3) + 8*(r>>2) + 4*hi;
    xvA[r] = xw[(long)rowoff*512];
  }
  #pragma unroll
  for (int it = 0; it < 8; ++it) {
    // prefetch next iteration's x BEFORE this iteration's MFMA chain
    if (it < 7) {
      #pragma unroll
      for (int r = 0; r < 16; ++r) {
        int rowoff = (r&3) + 8*(r>>2) + 4*hi;
        xvB[r] = xw[(long)rowoff*512 + (it+1)*32];
      }
    }
    const short* wrow = WoT + ((long)(wc*256 + it*32 + l31))*256 + hi*8;
    f32x16 ao0 = {}, ao1 = {};
    #pragma unroll
    for (int ns2 = 0; ns2 < 8; ++ns2) {
      bf16x8 b0 = *(const bf16x8*)(wrow + (2*ns2  )*16);
      bf16x8 b1 = *(const bf16x8*)(wrow + (2*ns2+1)*16);
      ao0 = mfma32(ya[2*ns2  ], b0, ao0);
      ao1 = mfma32(ya[2*ns2+1], b1, ao1);
    }
    #pragma unroll
    for (int r = 0; r < 16; ++r) {
      int rowoff = (r&3) + 8*(r>>2) + 4*hi;
      ow[(long)rowoff*512 + it*32] = ao0[r] + ao1[r] + xvA[r];
    }
    #pragma unroll
    for (int r = 0; r < 16; ++r) xvA[r] = xvB[r];
  }
}

extern "C" void kernel_launch(void* const* d_in, const int* in_sizes, int n_in,
                              void* d_out, int out_size, void* d_ws, size_t ws_size,
                              hipStream_t stream) {
  const float* x  = (const float*)d_in[0];
  const float* Wf = (const float*)d_in[1];
  const float* Wg = (const float*)d_in[2];
  const float* Wh = (const float*)d_in[3];
  const float* Wo = (const float*)d_in[4];
  float* out = (float*)d_out;

  // workspace carve-up (bf16 elements)
  short* xp  = (short*)d_ws;                    // [16*1024, 512]
  short* fb  = xp  + (long)16*1024*512;         // [65536, 64]
  short* gb  = fb  + (long)65536*64;            // [16384, 64]
  short* hb  = gb  + (long)16384*64;            // [16384, 256]
  short* hTb = hb  + (long)16384*256;           // [16*256, 1024]
  short* yb  = hTb + (long)16*256*1024;         // [65536, 256]
  short* WfT = yb  + (long)65536*256;           // [64, 512]
  short* WgT = WfT + 64*512;
  short* WhT = WgT + 64*512;
  short* WoT = WhT + 256*512;

  hipFuncSetAttribute((const void*)attn_kernel,
                      hipFuncAttributeMaxDynamicSharedMemorySize, 81920);

  const float LOG2E = 1.44269504f;
  prep_weights<<<1536, 256, 0, stream>>>(Wf, Wg, Wh, Wo, WfT, WgT, WhT, WoT);
  gemm_k512<true , true ><<<dim3(512, 1), 256, 0, stream>>>((const void*)x,  WfT, fb, 64,  xp, LOG2E);
  gemm_k512<false, false><<<dim3(128, 1), 256, 0, stream>>>((const void*)xp, WgT, gb, 64,  nullptr, 1.0f);
  gemm_k512<false, false><<<dim3(128, 4), 256, 0, stream>>>((const void*)xp, WhT, hb, 256, nullptr, 1.0f);
  transpose_h <<<dim3(16, 4, 16), 256, 0, stream>>>(hb, hTb);
  attn_kernel <<<512, 256, 81920, stream>>>(fb, gb, hTb, yb);
  gemm_out    <<<1024, 256, 0, stream>>>(yb, WoT, x, out);
}

// Round 10
// 222.549 us; speedup vs baseline: 1.1576x; 1.1576x over previous
//
#include <hip/hip_runtime.h>

// Attention_86423331930517 — MI355X bf16-MFMA implementation, round 10.
// B=16, H=W=64, C=512, HW=4096, P=1024 pooled pixels, D=64 (qk dim), DV=256 (v dim).
// Round-10 change: gemm_out only. R8/R9 post-mortem: x-path is MLP-bound — register
// staging can't keep enough loads in flight (compiler sinks/serializes them). Now x is
// DMA-staged to LDS in double-buffered 64x64 chunks via global_load_lds with counted
// s_waitcnt vmcnt(4) (the attn-pattern pipeline: zero VGPR cost, loads span a full
// iteration of MFMA+stores). MFMA/ya/store mapping identical to the validated R8 code.

#define DEVI static __device__ __forceinline__

typedef float f32x4  __attribute__((ext_vector_type(4)));
typedef float f32x16 __attribute__((ext_vector_type(16)));
typedef short bf16x8 __attribute__((ext_vector_type(8)));

DEVI short f2bf(float f) {
  union { float f; unsigned u; } v; v.f = f;
  unsigned r = v.u + 0x7FFFu + ((v.u >> 16) & 1u);   // RNE
  return (short)(r >> 16);
}
DEVI float b2f(short s) {
  union { unsigned u; float f; } v; v.u = ((unsigned)(unsigned short)s) << 16; return v.f;
}
DEVI unsigned cvtpk(float lo, float hi) {        // dst = {bf16(lo) | bf16(hi)<<16}, RNE
  unsigned r;
  asm("v_cvt_pk_bf16_f32 %0, %1, %2" : "=v"(r) : "v"(lo), "v"(hi));
  return r;
}
DEVI f32x4 mfma16(bf16x8 a, bf16x8 b, f32x4 c) {
  return __builtin_amdgcn_mfma_f32_16x16x32_bf16(a, b, c, 0, 0, 0);
}
DEVI f32x16 mfma32(bf16x8 a, bf16x8 b, f32x16 c) {
  return __builtin_amdgcn_mfma_f32_32x32x16_bf16(a, b, c, 0, 0, 0);
}
DEVI void gload16(const short* gsrc, short* lds) {
  __builtin_amdgcn_global_load_lds(
      (const __attribute__((address_space(1))) void*)gsrc,
      (__attribute__((address_space(3))) void*)lds, 16, 0, 0);
}

// ---------------- weights: cast to bf16 and transpose so B-operand rows are k-contiguous
__global__ __launch_bounds__(256) void prep_weights(
    const float* __restrict__ Wf, const float* __restrict__ Wg,
    const float* __restrict__ Wh, const float* __restrict__ Wo,
    short* __restrict__ WfT, short* __restrict__ WgT,
    short* __restrict__ WhT, short* __restrict__ WoT) {
  int i = blockIdx.x * 256 + threadIdx.x;   // 0..393215 exactly
  const float* src; short* dst; int K, N, e;
  if (i < 32768)       { src = Wf; dst = WfT; K = 512; N = 64;  e = i; }
  else if (i < 65536)  { src = Wg; dst = WgT; K = 512; N = 64;  e = i - 32768; }
  else if (i < 196608) { src = Wh; dst = WhT; K = 512; N = 256; e = i - 65536; }
  else                 { src = Wo; dst = WoT; K = 256; N = 512; e = i - 196608; }
  int n = e / K, k = e - n * K;            // dst[n][k] = src[k][n]
  dst[e] = f2bf(src[(long)k * N + n]);
}

// ---------------- staging helper: tile of `rows` x 64 bf16 into XOR-swizzled LDS -------
template<bool SRC_F32>
DEVI void stage64(short* lds, const void* gsrc, int rows, int stride, int tid) {
  const int chunks = rows * 8;
  for (int c = tid; c < chunks; c += 256) {
    int row = c >> 3, slot = c & 7;
    int dstb = row*128 + ((slot ^ (row & 7)) << 4);
    if (SRC_F32) {
      const float* s = (const float*)gsrc + (long)row*stride + slot*8;
      float4 u0 = *(const float4*)s;
      float4 u1 = *(const float4*)(s + 4);
      union { unsigned u[4]; bf16x8 v; } pk;
      pk.u[0] = cvtpk(u0.x, u0.y); pk.u[1] = cvtpk(u0.z, u0.w);
      pk.u[2] = cvtpk(u1.x, u1.y); pk.u[3] = cvtpk(u1.z, u1.w);
      *(bf16x8*)((char*)lds + dstb) = pk.v;
    } else {
      *(bf16x8*)((char*)lds + dstb) =
          *(const bf16x8*)((const short*)gsrc + (long)row*stride + slot*8);
    }
  }
}

// ---------------- generic K=512 GEMM: C[M,Nfull] = A[M,512] @ BT[N,512]^T (bf16 out) ---
// cscale: applied at C-write (f-GEMM uses log2(e) so attn can use raw exp2).
template<bool A_F32, bool POOL>
__global__ __launch_bounds__(256) void gemm_k512(const void* __restrict__ A,
    const short* __restrict__ BT, short* __restrict__ C, int Nfull,
    short* __restrict__ xp, float cscale) {
  __shared__ short As[128*64];
  __shared__ short Bs[64*64];
  const int m0 = blockIdx.x * 128;
  const int n0 = blockIdx.y * 64;
  const int tid = threadIdx.x, w = tid >> 6, lane = tid & 63;
  const int l15 = lane & 15, lhi = lane >> 4;
  const int wr = w >> 1, wc = w & 1;
  f32x4 acc[4][2] = {};
  for (int kt = 0; kt < 8; ++kt) {
    const int k0 = kt * 64;
    if constexpr (A_F32)
      stage64<true >(As, (const float*)A + (long)m0*512 + k0, 128, 512, tid);
    else
      stage64<false>(As, (const short*)A + (long)m0*512 + k0, 128, 512, tid);
    stage64<false>(Bs, BT + (long)n0*512 + k0, 64, 512, tid);
    __syncthreads();
    if constexpr (POOL) {
      const long pr0 = (long)(m0 >> 12)*1024 + ((m0 & 4095) >> 7)*32;
      int wp = tid >> 3, cs = tid & 7;
      const char* Ab = (const char*)As;
      bf16x8 v00 = *(const bf16x8*)(Ab + (2*wp  )*128 + ((cs ^ ((2*wp  )&7))<<4));
      bf16x8 v01 = *(const bf16x8*)(Ab + (2*wp+1)*128 + ((cs ^ ((2*wp+1)&7))<<4));
      bf16x8 v10 = *(const bf16x8*)(Ab + (64+2*wp)*128 + ((cs ^ ((2*wp  )&7))<<4));
      bf16x8 v11 = *(const bf16x8*)(Ab + (65+2*wp)*128 + ((cs ^ ((2*wp+1)&7))<<4));
      float s[8];
      #pragma unroll
      for (int j = 0; j < 8; ++j)
        s[j] = 0.25f*(b2f(v00[j])+b2f(v01[j])+b2f(v10[j])+b2f(v11[j]));
      union { unsigned u[4]; bf16x8 v; } pk;
      pk.u[0] = cvtpk(s[0], s[1]); pk.u[1] = cvtpk(s[2], s[3]);
      pk.u[2] = cvtpk(s[4], s[5]); pk.u[3] = cvtpk(s[6], s[7]);
      *(bf16x8*)(xp + (pr0 + wp)*512 + k0 + cs*8) = pk.v;
    }
    bf16x8 af[4][2], bfr[2][2];
    #pragma unroll
    for (int mi = 0; mi < 4; ++mi)
      #pragma unroll
      for (int ks = 0; ks < 2; ++ks) {
        int m = wr*64 + mi*16 + l15;
        int slot = lhi + ks*4;
        af[mi][ks] = *(const bf16x8*)((const char*)As + m*128 + ((slot ^ (m & 7)) << 4));
      }
    #pragma unroll
    for (int ni = 0; ni < 2; ++ni)
      #pragma unroll
      for (int ks = 0; ks < 2; ++ks) {
        int n = wc*32 + ni*16 + l15;
        int slot = lhi + ks*4;
        bfr[ni][ks] = *(const bf16x8*)((const char*)Bs + n*128 + ((slot ^ (n & 7)) << 4));
      }
    #pragma unroll
    for (int ks = 0; ks < 2; ++ks)
      #pragma unroll
      for (int mi = 0; mi < 4; ++mi)
        #pragma unroll
        for (int ni = 0; ni < 2; ++ni)
          acc[mi][ni] = mfma16(af[mi][ks], bfr[ni][ks], acc[mi][ni]);
    __syncthreads();
  }
  #pragma unroll
  for (int mi = 0; mi < 4; ++mi)
    #pragma unroll
    for (int ni = 0; ni < 2; ++ni)
      #pragma unroll
      for (int r = 0; r < 4; ++r) {
        long row = m0 + wr*64 + mi*16 + lhi*4 + r;
        int col = n0 + wc*32 + ni*16 + l15;
        C[row * (long)Nfull + col] = f2bf(acc[mi][ni][r] * cscale);
      }
}

// ---------------- h[16*1024,256] -> hT[16*256,1024] (bf16 transpose) -------------------
__global__ __launch_bounds__(256) void transpose_h(const short* __restrict__ h,
                                                   short* __restrict__ hT) {
  __shared__ short t[64][72];
  const int k0 = blockIdx.x * 64, n0 = blockIdx.y * 64, b = blockIdx.z;
  const int tid = threadIdx.x;
  {
    int row = tid >> 2, cch = (tid & 3) * 16;
    const short* src = h + ((long)b*1024 + k0 + row) * 256 + n0 + cch;
    *(bf16x8*)&t[row][cch]     = *(const bf16x8*)src;
    *(bf16x8*)&t[row][cch + 8] = *(const bf16x8*)(src + 8);
  }
  __syncthreads();
  {
    int n = tid >> 2, kch = (tid & 3) * 16;
    bf16x8 lo, hi;
    #pragma unroll
    for (int j = 0; j < 8; ++j) { lo[j] = t[kch + j][n]; hi[j] = t[kch + 8 + j][n]; }
    short* dst = hT + ((long)b*256 + n0 + n) * 1024 + k0 + kch;
    *(bf16x8*)dst       = lo;
    *(bf16x8*)(dst + 8) = hi;
  }
}

// ---------------- fused attention, 32x32x16 MFMA, QBLK=128, 4 waves, 2 blocks/CU -------
// Swapped QK^T: S = mfma(g, f) -> q=lane&31 lane-local (f pre-scaled by log2e -> raw
// exp2). P assembled IN-REGISTER via v_cvt_pk_bf16_f32 + v_permlane32_swap_b32.
// Swapped PV: y = mfma(hT, P). Counted s_waitcnt vmcnt(10) + raw barriers.
// Flat grid 512 with XCD swizzle: xcd=bid&7 owns batches {2*xcd, 2*xcd+1} -> K/V L2-local.
// Epilogue: normalize, per-wave LDS round-trip -> coalesced y stores.
__global__ __launch_bounds__(256, 2) void attn_kernel(const short* __restrict__ f,
    const short* __restrict__ g, const short* __restrict__ hT,
    short* __restrict__ y) {
  extern __shared__ __align__(16) char smem[];
  const int bid = blockIdx.x;
  const int xcd = bid & 7, idx = bid >> 3;
  const int b = xcd*2 + (idx >> 5);
  const int q0 = (idx & 31) * 128;
  const int tid = threadIdx.x, w = tid >> 6, lane = tid & 63;
  const int l31 = lane & 31, hi = lane >> 5;

  bf16x8 fq[4];
  {
    const short* frow = f + ((long)b*4096 + q0 + w*32 + l31) * 64;
    #pragma unroll
    for (int ks = 0; ks < 4; ++ks) fq[ks] = *(const bf16x8*)(frow + ks*16 + hi*8);
  }

  f32x16 acc2[8] = {};     // [nc2] : n = nc2*32 + (g&3)+8*(g>>2)+4*hi, q = l31
  float rsq = 0.f;

  auto stage = [&](int buf, int kt) {   // 10 gload16 per wave per call
    const int k0 = kt * 64;
    short* gbuf = (short*)(smem + buf*8192);
    short* hbuf = (short*)(smem + 16384 + buf*32768);
    #pragma unroll
    for (int it = 0; it < 2; ++it) {          // g: 64 rows x 8 slots = 512 chunks
      int c = it*256 + w*64 + lane;
      int row = c >> 3, gslot = (c & 7) ^ (row & 7);
      gload16(g + ((long)b*1024 + k0 + row)*64 + gslot*8, gbuf + (it*256 + w*64)*8);
    }
    #pragma unroll
    for (int it = 0; it < 8; ++it) {          // hT: 256 rows x 8 slots = 2048 chunks
      int c = it*256 + w*64 + lane;
      int row = c >> 3, gslot = (c & 7) ^ (row & 7);
      gload16(hT + ((long)b*256 + row)*1024 + k0 + gslot*8, hbuf + (it*256 + w*64)*8);
    }
  };

  stage(0, 0);
  int cur = 0;
  for (int kt = 0; kt < 16; ++kt) {
    if (kt < 15) {
      stage(cur ^ 1, kt + 1);
      // wait only for CURRENT tile's 10 loads (issued last iter); next's 10 stay in flight
      asm volatile("s_waitcnt vmcnt(10)" ::: "memory");
    } else {
      asm volatile("s_waitcnt vmcnt(0)" ::: "memory");
    }
    __builtin_amdgcn_s_barrier();          // current buffer visible to all waves
    const char* gcur = (const char*)(smem + cur*8192);
    const char* hcur = (const char*)(smem + 16384 + cur*32768);
    // ---- QK^T (swapped) + exp2 + in-register P^T fragment assembly ----
    bf16x8 pa[4];
    #pragma unroll
    for (int kc2 = 0; kc2 < 2; ++kc2) {
      f32x16 s2 = {};
      #pragma unroll
      for (int ks = 0; ks < 4; ++ks) {
        int key = kc2*32 + l31;
        bf16x8 gb = *(const bf16x8*)(gcur + key*128 + (((ks*2 + hi) ^ (l31 & 7)) << 4));
        s2 = mfma32(gb, fq[ks], s2);
      }
      #pragma unroll
      for (int fh = 0; fh < 2; ++fh) {
        const int G = fh*8;
        float e0 = exp2f(s2[G+0]), e1 = exp2f(s2[G+1]);
        float e2 = exp2f(s2[G+2]), e3 = exp2f(s2[G+3]);
        float e4 = exp2f(s2[G+4]), e5 = exp2f(s2[G+5]);
        float e6 = exp2f(s2[G+6]), e7 = exp2f(s2[G+7]);
        rsq += ((e0 + e1) + (e2 + e3)) + ((e4 + e5) + (e6 + e7));
        unsigned a0 = cvtpk(e0, e1), a1 = cvtpk(e2, e3);
        unsigned b0 = cvtpk(e4, e5), b1 = cvtpk(e6, e7);
        asm volatile("v_permlane32_swap_b32 %0, %1" : "+v"(b0), "+v"(a0));
        asm volatile("v_permlane32_swap_b32 %0, %1" : "+v"(b1), "+v"(a1));
        union { unsigned u[4]; bf16x8 v; } pk;
        pk.u[0] = a0; pk.u[1] = a1; pk.u[2] = b0; pk.u[3] = b1;
        pa[kc2*2 + fh] = pk.v;
      }
    }
    // ---- PV (swapped), P from registers ----
    __builtin_amdgcn_s_setprio(1);
    #pragma unroll
    for (int ks = 0; ks < 4; ++ks) {
      #pragma unroll
      for (int nc2 = 0; nc2 < 8; ++nc2) {
        int n = nc2*32 + l31;
        bf16x8 hb = *(const bf16x8*)(hcur + n*128 + (((ks*2 + hi) ^ (l31 & 7)) << 4));
        acc2[nc2] = mfma32(hb, pa[ks], acc2[nc2]);
      }
    }
    __builtin_amdgcn_s_setprio(0);
    __builtin_amdgcn_s_barrier();          // all waves done reading cur before overwrite
    cur ^= 1;
  }
  // ---- normalize + per-wave LDS round-trip -> coalesced y stores ----
  rsq += __shfl_xor(rsq, 32);
  float ri = 1.f / rsq;
  short* yw = (short*)(smem + w*16384);
  #pragma unroll
  for (int nc2 = 0; nc2 < 8; ++nc2) {
    #pragma unroll
    for (int fh = 0; fh < 2; ++fh) {
      const int G = fh*8;
      unsigned a0 = cvtpk(acc2[nc2][G+0]*ri, acc2[nc2][G+1]*ri);
      unsigned a1 = cvtpk(acc2[nc2][G+2]*ri, acc2[nc2][G+3]*ri);
      unsigned b0 = cvtpk(acc2[nc2][G+4]*ri, acc2[nc2][G+5]*ri);
      unsigned b1 = cvtpk(acc2[nc2][G+6]*ri, acc2[nc2][G+7]*ri);
      asm volatile("v_permlane32_swap_b32 %0, %1" : "+v"(b0), "+v"(a0));
      asm volatile("v_permlane32_swap_b32 %0, %1" : "+v"(b1), "+v"(a1));
      union { unsigned u[4]; bf16x8 v; } pk;
      pk.u[0] = a0; pk.u[1] = a1; pk.u[2] = b0; pk.u[3] = b1;
      int s = (nc2*2 + fh)*2 + hi;                       // logical 16B slot 0..31
      *(bf16x8*)(yw + l31*256 + ((s ^ l31) * 8)) = pk.v; // row=l31 (q), swizzled slot
    }
  }
  const long qb = (long)b*4096 + q0 + w*32;
  #pragma unroll
  for (int i = 0; i < 16; ++i) {
    int row = i*2 + hi;
    int s = l31 ^ row;                                   // logical slot at LDS pos l31
    bf16x8 v = *(const bf16x8*)(yw + row*256 + l31*8);
    *(bf16x8*)(y + (qb + row)*256 + s*8) = v;
  }
}

// ---------------- out = y[65536,256] @ WoT[512,256]^T + x (f32 out), streaming ---------
// UN-swapped orientation: A = y rows (LDS, staged once), B = WoT cols (L2-resident),
// C/D col = lane&31 -> x-loads and out-stores are contiguous 128B segments.
// Round-10: x DMA-staged to LDS in double-buffered 64x64 f32 chunks (global_load_lds,
// counted vmcnt(4)) -> deep MLP with zero VGPR cost. Per iteration: MFMA (WoT from L2,
// consumed) -> stage chunk it+1 -> vmcnt(4) -> barrier -> ds_read x + add + store ->
// barrier. LDS 64KB total -> 2 blocks/CU.
__global__ __launch_bounds__(256) void gemm_out(const short* __restrict__ y,
    const short* __restrict__ WoT, const float* __restrict__ x,
    float* __restrict__ out) {
  extern __shared__ __align__(16) char smem[];
  short* ys  = (short*)smem;                // 32 KB, 16B-slot XOR swizzle
  float* xs0 = (float*)(smem + 32768);      // 16 KB chunk buffer A
  float* xs1 = (float*)(smem + 49152);      // 16 KB chunk buffer B
  const int q0 = blockIdx.x * 64;
  const int tid = threadIdx.x, w = tid >> 6, lane = tid & 63;
  const int l31 = lane & 31, hi = lane >> 5;
  // stage y tile (8 gload16/thread)
  #pragma unroll
  for (int it = 0; it < 8; ++it) {
    int c = it*256 + tid;
    int row = c >> 5, gslot = (c & 31) ^ (row & 31);
    gload16(y + ((long)q0 + row)*256 + gslot*8, ys + c*8);
  }
  // x chunk stager: 64 rows x 64 cols f32 = 16KB = 4 gload16/thread, linear dest
  auto stagex = [&](float* dst, int it) {
    #pragma unroll
    for (int j = 0; j < 4; ++j) {
      int c = j*256 + tid;
      int row = c >> 4, cc = (c & 15) * 4;            // 16 x 16B chunks per row
      gload16((const short*)(x + ((long)q0 + row)*512 + it*64 + cc),
              (short*)(dst + c*4));
    }
  };
  stagex(xs0, 0);
  asm volatile("s_waitcnt vmcnt(4)" ::: "memory");   // y landed; x0 may stay in flight
  __builtin_amdgcn_s_barrier();
  const int wr = w & 1, wc = w >> 1;
  const int qr = wr*32 + l31;
  bf16x8 ya[16];
  #pragma unroll
  for (int kk = 0; kk < 16; ++kk)
    ya[kk] = *(const bf16x8*)(ys + qr*256 + (((kk*2 + hi) ^ l31) * 8));
  for (int it = 0; it < 8; ++it) {
    float* xcur = (it & 1) ? xs1 : xs0;
    float* xnxt = (it & 1) ? xs0 : xs1;
    const int c0 = it*64 + wc*32;
    const short* wrow = WoT + (long)(c0 + l31)*256 + hi*8;
    f32x16 ao0 = {}, ao1 = {};
    #pragma unroll
    for (int ns2 = 0; ns2 < 8; ++ns2) {
      bf16x8 b0 = *(const bf16x8*)(wrow + (2*ns2  )*16);
      bf16x8 b1 = *(const bf16x8*)(wrow + (2*ns2+1)*16);
      ao0 = mfma32(ya[2*ns2  ], b0, ao0);
      ao1 = mfma32(ya[2*ns2+1], b1, ao1);
    }
    if (it < 7) {
      stagex(xnxt, it + 1);                            // issue next chunk's DMA
      asm volatile("s_waitcnt vmcnt(4)" ::: "memory"); // chunk it landed (4 newer ok)
    } else {
      asm volatile("s_waitcnt vmcnt(0)" ::: "memory");
    }
    __builtin_amdgcn_s_barrier();                      // all waves' chunk-it in LDS
    #pragma unroll
    for (int r = 0; r < 16; ++r) {
      int rowoff = (r&3) + 8*(r>>2) + 4*hi;
      float xv = xcur[(wr*32 + rowoff)*64 + wc*32 + l31];
      out[((long)q0 + wr*32 + rowoff)*512 + c0 + l31] = ao0[r] + ao1[r] + xv;
    }
    __builtin_amdgcn_s_barrier();                      // reads done before next DMA
  }
}

extern "C" void kernel_launch(void* const* d_in, const int* in_sizes, int n_in,
                              void* d_out, int out_size, void* d_ws, size_t ws_size,
                              hipStream_t stream) {
  const float* x  = (const float*)d_in[0];
  const float* Wf = (const float*)d_in[1];
  const float* Wg = (const float*)d_in[2];
  const float* Wh = (const float*)d_in[3];
  const float* Wo = (const float*)d_in[4];
  float* out = (float*)d_out;

  // workspace carve-up (bf16 elements)
  short* xp  = (short*)d_ws;                    // [16*1024, 512]
  short* fb  = xp  + (long)16*1024*512;         // [65536, 64]
  short* gb  = fb  + (long)65536*64;            // [16384, 64]
  short* hb  = gb  + (long)16384*64;            // [16384, 256]
  short* hTb = hb  + (long)16384*256;           // [16*256, 1024]
  short* yb  = hTb + (long)16*256*1024;         // [65536, 256]
  short* WfT = yb  + (long)65536*256;           // [64, 512]
  short* WgT = WfT + 64*512;
  short* WhT = WgT + 64*512;
  short* WoT = WhT + 256*512;

  hipFuncSetAttribute((const void*)attn_kernel,
                      hipFuncAttributeMaxDynamicSharedMemorySize, 81920);
  hipFuncSetAttribute((const void*)gemm_out,
                      hipFuncAttributeMaxDynamicSharedMemorySize, 65536);

  const float LOG2E = 1.44269504f;
  prep_weights<<<1536, 256, 0, stream>>>(Wf, Wg, Wh, Wo, WfT, WgT, WhT, WoT);
  gemm_k512<true , true ><<<dim3(512, 1), 256, 0, stream>>>((const void*)x,  WfT, fb, 64,  xp, LOG2E);
  gemm_k512<false, false><<<dim3(128, 1), 256, 0, stream>>>((const void*)xp, WgT, gb, 64,  nullptr, 1.0f);
  gemm_k512<false, false><<<dim3(128, 4), 256, 0, stream>>>((const void*)xp, WhT, hb, 256, nullptr, 1.0f);
  transpose_h <<<dim3(16, 4, 16), 256, 0, stream>>>(hb, hTb);
  attn_kernel <<<512, 256, 81920, stream>>>(fb, gb, hTb, yb);
  gemm_out    <<<1024, 256, 65536, stream>>>(yb, WoT, x, out);
}

// Round 11
// 213.621 us; speedup vs baseline: 1.2059x; 1.0418x over previous
//
#include <hip/hip_runtime.h>

// Attention_86423331930517 — MI355X bf16-MFMA implementation, round 11.
// B=16, H=W=64, C=512, HW=4096, P=1024 pooled pixels, D=64 (qk dim), DV=256 (v dim).
// Round-11 change: gemm_out only. R10 post-mortem: WoT vector loads issued right
// before each MFMA made the compiler's inserted waitcnt ~vmcnt(0) -> drained the
// prev iteration's 16 stores + async x-DMA every iteration (vmcnt is in-order).
// Fix: hoist all 16 WoT loads to the TOP of the iteration, BEFORE the x-DMA issue,
// so the compiler's WoT wait is vmcnt(4) and stores/DMA stay in flight.

#define DEVI static __device__ __forceinline__

typedef float f32x4  __attribute__((ext_vector_type(4)));
typedef float f32x16 __attribute__((ext_vector_type(16)));
typedef short bf16x8 __attribute__((ext_vector_type(8)));

DEVI short f2bf(float f) {
  union { float f; unsigned u; } v; v.f = f;
  unsigned r = v.u + 0x7FFFu + ((v.u >> 16) & 1u);   // RNE
  return (short)(r >> 16);
}
DEVI float b2f(short s) {
  union { unsigned u; float f; } v; v.u = ((unsigned)(unsigned short)s) << 16; return v.f;
}
DEVI unsigned cvtpk(float lo, float hi) {        // dst = {bf16(lo) | bf16(hi)<<16}, RNE
  unsigned r;
  asm("v_cvt_pk_bf16_f32 %0, %1, %2" : "=v"(r) : "v"(lo), "v"(hi));
  return r;
}
DEVI f32x4 mfma16(bf16x8 a, bf16x8 b, f32x4 c) {
  return __builtin_amdgcn_mfma_f32_16x16x32_bf16(a, b, c, 0, 0, 0);
}
DEVI f32x16 mfma32(bf16x8 a, bf16x8 b, f32x16 c) {
  return __builtin_amdgcn_mfma_f32_32x32x16_bf16(a, b, c, 0, 0, 0);
}
DEVI void gload16(const short* gsrc, short* lds) {
  __builtin_amdgcn_global_load_lds(
      (const __attribute__((address_space(1))) void*)gsrc,
      (__attribute__((address_space(3))) void*)lds, 16, 0, 0);
}

// ---------------- weights: cast to bf16 and transpose so B-operand rows are k-contiguous
__global__ __launch_bounds__(256) void prep_weights(
    const float* __restrict__ Wf, const float* __restrict__ Wg,
    const float* __restrict__ Wh, const float* __restrict__ Wo,
    short* __restrict__ WfT, short* __restrict__ WgT,
    short* __restrict__ WhT, short* __restrict__ WoT) {
  int i = blockIdx.x * 256 + threadIdx.x;   // 0..393215 exactly
  const float* src; short* dst; int K, N, e;
  if (i < 32768)       { src = Wf; dst = WfT; K = 512; N = 64;  e = i; }
  else if (i < 65536)  { src = Wg; dst = WgT; K = 512; N = 64;  e = i - 32768; }
  else if (i < 196608) { src = Wh; dst = WhT; K = 512; N = 256; e = i - 65536; }
  else                 { src = Wo; dst = WoT; K = 256; N = 512; e = i - 196608; }
  int n = e / K, k = e - n * K;            // dst[n][k] = src[k][n]
  dst[e] = f2bf(src[(long)k * N + n]);
}

// ---------------- staging helper: tile of `rows` x 64 bf16 into XOR-swizzled LDS -------
template<bool SRC_F32>
DEVI void stage64(short* lds, const void* gsrc, int rows, int stride, int tid) {
  const int chunks = rows * 8;
  for (int c = tid; c < chunks; c += 256) {
    int row = c >> 3, slot = c & 7;
    int dstb = row*128 + ((slot ^ (row & 7)) << 4);
    if (SRC_F32) {
      const float* s = (const float*)gsrc + (long)row*stride + slot*8;
      float4 u0 = *(const float4*)s;
      float4 u1 = *(const float4*)(s + 4);
      union { unsigned u[4]; bf16x8 v; } pk;
      pk.u[0] = cvtpk(u0.x, u0.y); pk.u[1] = cvtpk(u0.z, u0.w);
      pk.u[2] = cvtpk(u1.x, u1.y); pk.u[3] = cvtpk(u1.z, u1.w);
      *(bf16x8*)((char*)lds + dstb) = pk.v;
    } else {
      *(bf16x8*)((char*)lds + dstb) =
          *(const bf16x8*)((const short*)gsrc + (long)row*stride + slot*8);
    }
  }
}

// ---------------- generic K=512 GEMM: C[M,Nfull] = A[M,512] @ BT[N,512]^T (bf16 out) ---
// cscale: applied at C-write (f-GEMM uses log2(e) so attn can use raw exp2).
template<bool A_F32, bool POOL>
__global__ __launch_bounds__(256) void gemm_k512(const void* __restrict__ A,
    const short* __restrict__ BT, short* __restrict__ C, int Nfull,
    short* __restrict__ xp, float cscale) {
  __shared__ short As[128*64];
  __shared__ short Bs[64*64];
  const int m0 = blockIdx.x * 128;
  const int n0 = blockIdx.y * 64;
  const int tid = threadIdx.x, w = tid >> 6, lane = tid & 63;
  const int l15 = lane & 15, lhi = lane >> 4;
  const int wr = w >> 1, wc = w & 1;
  f32x4 acc[4][2] = {};
  for (int kt = 0; kt < 8; ++kt) {
    const int k0 = kt * 64;
    if constexpr (A_F32)
      stage64<true >(As, (const float*)A + (long)m0*512 + k0, 128, 512, tid);
    else
      stage64<false>(As, (const short*)A + (long)m0*512 + k0, 128, 512, tid);
    stage64<false>(Bs, BT + (long)n0*512 + k0, 64, 512, tid);
    __syncthreads();
    if constexpr (POOL) {
      const long pr0 = (long)(m0 >> 12)*1024 + ((m0 & 4095) >> 7)*32;
      int wp = tid >> 3, cs = tid & 7;
      const char* Ab = (const char*)As;
      bf16x8 v00 = *(const bf16x8*)(Ab + (2*wp  )*128 + ((cs ^ ((2*wp  )&7))<<4));
      bf16x8 v01 = *(const bf16x8*)(Ab + (2*wp+1)*128 + ((cs ^ ((2*wp+1)&7))<<4));
      bf16x8 v10 = *(const bf16x8*)(Ab + (64+2*wp)*128 + ((cs ^ ((2*wp  )&7))<<4));
      bf16x8 v11 = *(const bf16x8*)(Ab + (65+2*wp)*128 + ((cs ^ ((2*wp+1)&7))<<4));
      float s[8];
      #pragma unroll
      for (int j = 0; j < 8; ++j)
        s[j] = 0.25f*(b2f(v00[j])+b2f(v01[j])+b2f(v10[j])+b2f(v11[j]));
      union { unsigned u[4]; bf16x8 v; } pk;
      pk.u[0] = cvtpk(s[0], s[1]); pk.u[1] = cvtpk(s[2], s[3]);
      pk.u[2] = cvtpk(s[4], s[5]); pk.u[3] = cvtpk(s[6], s[7]);
      *(bf16x8*)(xp + (pr0 + wp)*512 + k0 + cs*8) = pk.v;
    }
    bf16x8 af[4][2], bfr[2][2];
    #pragma unroll
    for (int mi = 0; mi < 4; ++mi)
      #pragma unroll
      for (int ks = 0; ks < 2; ++ks) {
        int m = wr*64 + mi*16 + l15;
        int slot = lhi + ks*4;
        af[mi][ks] = *(const bf16x8*)((const char*)As + m*128 + ((slot ^ (m & 7)) << 4));
      }
    #pragma unroll
    for (int ni = 0; ni < 2; ++ni)
      #pragma unroll
      for (int ks = 0; ks < 2; ++ks) {
        int n = wc*32 + ni*16 + l15;
        int slot = lhi + ks*4;
        bfr[ni][ks] = *(const bf16x8*)((const char*)Bs + n*128 + ((slot ^ (n & 7)) << 4));
      }
    #pragma unroll
    for (int ks = 0; ks < 2; ++ks)
      #pragma unroll
      for (int mi = 0; mi < 4; ++mi)
        #pragma unroll
        for (int ni = 0; ni < 2; ++ni)
          acc[mi][ni] = mfma16(af[mi][ks], bfr[ni][ks], acc[mi][ni]);
    __syncthreads();
  }
  #pragma unroll
  for (int mi = 0; mi < 4; ++mi)
    #pragma unroll
    for (int ni = 0; ni < 2; ++ni)
      #pragma unroll
      for (int r = 0; r < 4; ++r) {
        long row = m0 + wr*64 + mi*16 + lhi*4 + r;
        int col = n0 + wc*32 + ni*16 + l15;
        C[row * (long)Nfull + col] = f2bf(acc[mi][ni][r] * cscale);
      }
}

// ---------------- h[16*1024,256] -> hT[16*256,1024] (bf16 transpose) -------------------
__global__ __launch_bounds__(256) void transpose_h(const short* __restrict__ h,
                                                   short* __restrict__ hT) {
  __shared__ short t[64][72];
  const int k0 = blockIdx.x * 64, n0 = blockIdx.y * 64, b = blockIdx.z;
  const int tid = threadIdx.x;
  {
    int row = tid >> 2, cch = (tid & 3) * 16;
    const short* src = h + ((long)b*1024 + k0 + row) * 256 + n0 + cch;
    *(bf16x8*)&t[row][cch]     = *(const bf16x8*)src;
    *(bf16x8*)&t[row][cch + 8] = *(const bf16x8*)(src + 8);
  }
  __syncthreads();
  {
    int n = tid >> 2, kch = (tid & 3) * 16;
    bf16x8 lo, hi;
    #pragma unroll
    for (int j = 0; j < 8; ++j) { lo[j] = t[kch + j][n]; hi[j] = t[kch + 8 + j][n]; }
    short* dst = hT + ((long)b*256 + n0 + n) * 1024 + k0 + kch;
    *(bf16x8*)dst       = lo;
    *(bf16x8*)(dst + 8) = hi;
  }
}

// ---------------- fused attention, 32x32x16 MFMA, QBLK=128, 4 waves, 2 blocks/CU -------
// Swapped QK^T: S = mfma(g, f) -> q=lane&31 lane-local (f pre-scaled by log2e -> raw
// exp2). P assembled IN-REGISTER via v_cvt_pk_bf16_f32 + v_permlane32_swap_b32.
// Swapped PV: y = mfma(hT, P). Counted s_waitcnt vmcnt(10) + raw barriers.
// Flat grid 512 with XCD swizzle: xcd=bid&7 owns batches {2*xcd, 2*xcd+1} -> K/V L2-local.
// Epilogue: normalize, per-wave LDS round-trip -> coalesced y stores.
__global__ __launch_bounds__(256, 2) void attn_kernel(const short* __restrict__ f,
    const short* __restrict__ g, const short* __restrict__ hT,
    short* __restrict__ y) {
  extern __shared__ __align__(16) char smem[];
  const int bid = blockIdx.x;
  const int xcd = bid & 7, idx = bid >> 3;
  const int b = xcd*2 + (idx >> 5);
  const int q0 = (idx & 31) * 128;
  const int tid = threadIdx.x, w = tid >> 6, lane = tid & 63;
  const int l31 = lane & 31, hi = lane >> 5;

  bf16x8 fq[4];
  {
    const short* frow = f + ((long)b*4096 + q0 + w*32 + l31) * 64;
    #pragma unroll
    for (int ks = 0; ks < 4; ++ks) fq[ks] = *(const bf16x8*)(frow + ks*16 + hi*8);
  }

  f32x16 acc2[8] = {};     // [nc2] : n = nc2*32 + (g&3)+8*(g>>2)+4*hi, q = l31
  float rsq = 0.f;

  auto stage = [&](int buf, int kt) {   // 10 gload16 per wave per call
    const int k0 = kt * 64;
    short* gbuf = (short*)(smem + buf*8192);
    short* hbuf = (short*)(smem + 16384 + buf*32768);
    #pragma unroll
    for (int it = 0; it < 2; ++it) {          // g: 64 rows x 8 slots = 512 chunks
      int c = it*256 + w*64 + lane;
      int row = c >> 3, gslot = (c & 7) ^ (row & 7);
      gload16(g + ((long)b*1024 + k0 + row)*64 + gslot*8, gbuf + (it*256 + w*64)*8);
    }
    #pragma unroll
    for (int it = 0; it < 8; ++it) {          // hT: 256 rows x 8 slots = 2048 chunks
      int c = it*256 + w*64 + lane;
      int row = c >> 3, gslot = (c & 7) ^ (row & 7);
      gload16(hT + ((long)b*256 + row)*1024 + k0 + gslot*8, hbuf + (it*256 + w*64)*8);
    }
  };

  stage(0, 0);
  int cur = 0;
  for (int kt = 0; kt < 16; ++kt) {
    if (kt < 15) {
      stage(cur ^ 1, kt + 1);
      // wait only for CURRENT tile's 10 loads (issued last iter); next's 10 stay in flight
      asm volatile("s_waitcnt vmcnt(10)" ::: "memory");
    } else {
      asm volatile("s_waitcnt vmcnt(0)" ::: "memory");
    }
    __builtin_amdgcn_s_barrier();          // current buffer visible to all waves
    const char* gcur = (const char*)(smem + cur*8192);
    const char* hcur = (const char*)(smem + 16384 + cur*32768);
    // ---- QK^T (swapped) + exp2 + in-register P^T fragment assembly ----
    bf16x8 pa[4];
    #pragma unroll
    for (int kc2 = 0; kc2 < 2; ++kc2) {
      f32x16 s2 = {};
      #pragma unroll
      for (int ks = 0; ks < 4; ++ks) {
        int key = kc2*32 + l31;
        bf16x8 gb = *(const bf16x8*)(gcur + key*128 + (((ks*2 + hi) ^ (l31 & 7)) << 4));
        s2 = mfma32(gb, fq[ks], s2);
      }
      #pragma unroll
      for (int fh = 0; fh < 2; ++fh) {
        const int G = fh*8;
        float e0 = exp2f(s2[G+0]), e1 = exp2f(s2[G+1]);
        float e2 = exp2f(s2[G+2]), e3 = exp2f(s2[G+3]);
        float e4 = exp2f(s2[G+4]), e5 = exp2f(s2[G+5]);
        float e6 = exp2f(s2[G+6]), e7 = exp2f(s2[G+7]);
        rsq += ((e0 + e1) + (e2 + e3)) + ((e4 + e5) + (e6 + e7));
        unsigned a0 = cvtpk(e0, e1), a1 = cvtpk(e2, e3);
        unsigned b0 = cvtpk(e4, e5), b1 = cvtpk(e6, e7);
        asm volatile("v_permlane32_swap_b32 %0, %1" : "+v"(b0), "+v"(a0));
        asm volatile("v_permlane32_swap_b32 %0, %1" : "+v"(b1), "+v"(a1));
        union { unsigned u[4]; bf16x8 v; } pk;
        pk.u[0] = a0; pk.u[1] = a1; pk.u[2] = b0; pk.u[3] = b1;
        pa[kc2*2 + fh] = pk.v;
      }
    }
    // ---- PV (swapped), P from registers ----
    __builtin_amdgcn_s_setprio(1);
    #pragma unroll
    for (int ks = 0; ks < 4; ++ks) {
      #pragma unroll
      for (int nc2 = 0; nc2 < 8; ++nc2) {
        int n = nc2*32 + l31;
        bf16x8 hb = *(const bf16x8*)(hcur + n*128 + (((ks*2 + hi) ^ (l31 & 7)) << 4));
        acc2[nc2] = mfma32(hb, pa[ks], acc2[nc2]);
      }
    }
    __builtin_amdgcn_s_setprio(0);
    __builtin_amdgcn_s_barrier();          // all waves done reading cur before overwrite
    cur ^= 1;
  }
  // ---- normalize + per-wave LDS round-trip -> coalesced y stores ----
  rsq += __shfl_xor(rsq, 32);
  float ri = 1.f / rsq;
  short* yw = (short*)(smem + w*16384);
  #pragma unroll
  for (int nc2 = 0; nc2 < 8; ++nc2) {
    #pragma unroll
    for (int fh = 0; fh < 2; ++fh) {
      const int G = fh*8;
      unsigned a0 = cvtpk(acc2[nc2][G+0]*ri, acc2[nc2][G+1]*ri);
      unsigned a1 = cvtpk(acc2[nc2][G+2]*ri, acc2[nc2][G+3]*ri);
      unsigned b0 = cvtpk(acc2[nc2][G+4]*ri, acc2[nc2][G+5]*ri);
      unsigned b1 = cvtpk(acc2[nc2][G+6]*ri, acc2[nc2][G+7]*ri);
      asm volatile("v_permlane32_swap_b32 %0, %1" : "+v"(b0), "+v"(a0));
      asm volatile("v_permlane32_swap_b32 %0, %1" : "+v"(b1), "+v"(a1));
      union { unsigned u[4]; bf16x8 v; } pk;
      pk.u[0] = a0; pk.u[1] = a1; pk.u[2] = b0; pk.u[3] = b1;
      int s = (nc2*2 + fh)*2 + hi;                       // logical 16B slot 0..31
      *(bf16x8*)(yw + l31*256 + ((s ^ l31) * 8)) = pk.v; // row=l31 (q), swizzled slot
    }
  }
  const long qb = (long)b*4096 + q0 + w*32;
  #pragma unroll
  for (int i = 0; i < 16; ++i) {
    int row = i*2 + hi;
    int s = l31 ^ row;                                   // logical slot at LDS pos l31
    bf16x8 v = *(const bf16x8*)(yw + row*256 + l31*8);
    *(bf16x8*)(y + (qb + row)*256 + s*8) = v;
  }
}

// ---------------- out = y[65536,256] @ WoT[512,256]^T + x (f32 out), streaming ---------
// UN-swapped orientation: A = y rows (LDS, staged once), B = WoT cols (L2-resident),
// C/D col = lane&31 -> x-loads and out-stores are contiguous 128B segments.
// Round-11: WoT loads hoisted to the TOP of each iteration, before the x-DMA issue,
// so the compiler's inserted waitcnt for WoT is vmcnt(4) instead of vmcnt(0) —
// the async x pipeline and prior stores stay in flight across the MFMA phase.
__global__ __launch_bounds__(256) void gemm_out(const short* __restrict__ y,
    const short* __restrict__ WoT, const float* __restrict__ x,
    float* __restrict__ out) {
  extern __shared__ __align__(16) char smem[];
  short* ys  = (short*)smem;                // 32 KB, 16B-slot XOR swizzle
  float* xs0 = (float*)(smem + 32768);      // 16 KB chunk buffer A
  float* xs1 = (float*)(smem + 49152);      // 16 KB chunk buffer B
  const int q0 = blockIdx.x * 64;
  const int tid = threadIdx.x, w = tid >> 6, lane = tid & 63;
  const int l31 = lane & 31, hi = lane >> 5;
  // stage y tile (8 gload16/thread)
  #pragma unroll
  for (int it = 0; it < 8; ++it) {
    int c = it*256 + tid;
    int row = c >> 5, gslot = (c & 31) ^ (row & 31);
    gload16(y + ((long)q0 + row)*256 + gslot*8, ys + c*8);
  }
  // x chunk stager: 64 rows x 64 cols f32 = 16KB = 4 gload16/thread, linear dest
  auto stagex = [&](float* dst, int it) {
    #pragma unroll
    for (int j = 0; j < 4; ++j) {
      int c = j*256 + tid;
      int row = c >> 4, cc = (c & 15) * 4;            // 16 x 16B chunks per row
      gload16((const short*)(x + ((long)q0 + row)*512 + it*64 + cc),
              (short*)(dst + c*4));
    }
  };
  stagex(xs0, 0);
  asm volatile("s_waitcnt vmcnt(4)" ::: "memory");   // y landed; x0 may stay in flight
  __builtin_amdgcn_s_barrier();
  const int wr = w & 1, wc = w >> 1;
  const int qr = wr*32 + l31;
  bf16x8 ya[16];
  #pragma unroll
  for (int kk = 0; kk < 16; ++kk)
    ya[kk] = *(const bf16x8*)(ys + qr*256 + (((kk*2 + hi) ^ l31) * 8));
  for (int it = 0; it < 8; ++it) {
    float* xcur = (it & 1) ? xs1 : xs0;
    float* xnxt = (it & 1) ? xs0 : xs1;
    const int c0 = it*64 + wc*32;
    // 1) WoT loads FIRST (oldest vector ops of this iteration)
    const short* wrow = WoT + (long)(c0 + l31)*256 + hi*8;
    bf16x8 wo[16];
    #pragma unroll
    for (int ns = 0; ns < 16; ++ns) wo[ns] = *(const bf16x8*)(wrow + ns*16);
    // 2) issue next x chunk's DMA (newer than the WoT loads)
    if (it < 7) stagex(xnxt, it + 1);
    // 3) MFMA chain — compiler's wait for wo is vmcnt(4): DMA stays in flight
    f32x16 ao0 = {}, ao1 = {};
    #pragma unroll
    for (int ns2 = 0; ns2 < 8; ++ns2) {
      ao0 = mfma32(ya[2*ns2  ], wo[2*ns2  ], ao0);
      ao1 = mfma32(ya[2*ns2+1], wo[2*ns2+1], ao1);
    }
    // 4) chunk-it guaranteed resident (issued one full iteration ago)
    if (it < 7) asm volatile("s_waitcnt vmcnt(4)" ::: "memory");
    else        asm volatile("s_waitcnt vmcnt(0)" ::: "memory");
    __builtin_amdgcn_s_barrier();                      // all waves' chunk-it in LDS
    #pragma unroll
    for (int r = 0; r < 16; ++r) {
      int rowoff = (r&3) + 8*(r>>2) + 4*hi;
      float xv = xcur[(wr*32 + rowoff)*64 + wc*32 + l31];
      out[((long)q0 + wr*32 + rowoff)*512 + c0 + l31] = ao0[r] + ao1[r] + xv;
    }
    __builtin_amdgcn_s_barrier();                      // reads done before next DMA
  }
}

extern "C" void kernel_launch(void* const* d_in, const int* in_sizes, int n_in,
                              void* d_out, int out_size, void* d_ws, size_t ws_size,
                              hipStream_t stream) {
  const float* x  = (const float*)d_in[0];
  const float* Wf = (const float*)d_in[1];
  const float* Wg = (const float*)d_in[2];
  const float* Wh = (const float*)d_in[3];
  const float* Wo = (const float*)d_in[4];
  float* out = (float*)d_out;

  // workspace carve-up (bf16 elements)
  short* xp  = (short*)d_ws;                    // [16*1024, 512]
  short* fb  = xp  + (long)16*1024*512;         // [65536, 64]
  short* gb  = fb  + (long)65536*64;            // [16384, 64]
  short* hb  = gb  + (long)16384*64;            // [16384, 256]
  short* hTb = hb  + (long)16384*256;           // [16*256, 1024]
  short* yb  = hTb + (long)16*256*1024;         // [65536, 256]
  short* WfT = yb  + (long)65536*256;           // [64, 512]
  short* WgT = WfT + 64*512;
  short* WhT = WgT + 64*512;
  short* WoT = WhT + 256*512;

  hipFuncSetAttribute((const void*)attn_kernel,
                      hipFuncAttributeMaxDynamicSharedMemorySize, 81920);
  hipFuncSetAttribute((const void*)gemm_out,
                      hipFuncAttributeMaxDynamicSharedMemorySize, 65536);

  const float LOG2E = 1.44269504f;
  prep_weights<<<1536, 256, 0, stream>>>(Wf, Wg, Wh, Wo, WfT, WgT, WhT, WoT);
  gemm_k512<true , true ><<<dim3(512, 1), 256, 0, stream>>>((const void*)x,  WfT, fb, 64,  xp, LOG2E);
  gemm_k512<false, false><<<dim3(128, 1), 256, 0, stream>>>((const void*)xp, WgT, gb, 64,  nullptr, 1.0f);
  gemm_k512<false, false><<<dim3(128, 4), 256, 0, stream>>>((const void*)xp, WhT, hb, 256, nullptr, 1.0f);
  transpose_h <<<dim3(16, 4, 16), 256, 0, stream>>>(hb, hTb);
  attn_kernel <<<512, 256, 81920, stream>>>(fb, gb, hTb, yb);
  gemm_out    <<<1024, 256, 65536, stream>>>(yb, WoT, x, out);
}